// Round 7
// baseline (180.856 us; speedup 1.0000x reference)
//
#include <hip/hip_runtime.h>

#define LQ 768
#define DIN 256
#define DB 128
#define NH 8
#define DH 32

// ws float offsets
#define OFF_QB 0
#define OFF_KB (LQ*DIN)
#define OFF_VB (2*LQ*DIN)
#define OFF_GB (3*LQ*DIN)
#define OFF_W2 (4*LQ*DIN)
#define OFF_SC (OFF_W2 + DB*NH)
#define OFF_QK (OFF_SC + 16)     // qkT[q][k][h], 18.9 MB

// ---------------------------------------------------------------------------
// K1: proj (blocks 0..191, 4 rows each) + setup (block 192).
// proj: LN(x) -> q, k(scaled), v, gate rows. setup: W2/S/C fold of bias-LN.
// ---------------------------------------------------------------------------
__global__ __launch_bounds__(256) void projsetup_kernel(
    const float* __restrict__ x, const float* __restrict__ lnw, const float* __restrict__ lnb,
    const float* __restrict__ Wq, const float* __restrict__ Wk, const float* __restrict__ Wv,
    const float* __restrict__ Wg, const float* __restrict__ bg,
    const float* __restrict__ lbw, const float* __restrict__ lbb, const float* __restrict__ Wb,
    float* __restrict__ qb, float* __restrict__ kb, float* __restrict__ vb, float* __restrict__ gb,
    float* __restrict__ W2, float* __restrict__ SC)
{
    const int tid = threadIdx.x;

    if (blockIdx.x == 192) {            // ---- setup ----
        if (tid < 128) {
            const int d = tid, lane = d & 63, wv = d >> 6;
            float w = lbw[d], b = lbb[d];
            float pS[NH], pC[NH];
            #pragma unroll
            for (int h = 0; h < NH; h++) {
                float wb = Wb[d*NH + h];
                float w2 = w * wb;
                W2[d*NH + h] = w2;
                pS[h] = w2;
                pC[h] = b * wb;
            }
            #pragma unroll
            for (int m = 1; m <= 32; m <<= 1) {
                #pragma unroll
                for (int h = 0; h < NH; h++) { pS[h] += __shfl_xor(pS[h], m); pC[h] += __shfl_xor(pC[h], m); }
            }
            __shared__ float red[2][16];
            if (lane == 0) {
                #pragma unroll
                for (int h = 0; h < NH; h++) { red[wv][h] = pS[h]; red[wv][NH+h] = pC[h]; }
            }
            __syncthreads();
            if (d < 16) SC[d] = red[0][d] + red[1][d];
        }
        return;
    }

    // ---- proj: 4 rows per block ----
    const int lane = tid & 63, rr = tid >> 6;
    const int row = blockIdx.x * 4 + rr;
    __shared__ float xn[4][DIN];

    float4 xv = ((const float4*)x)[row * (DIN/4) + lane];
    float s  = xv.x + xv.y + xv.z + xv.w;
    float ss = xv.x*xv.x + xv.y*xv.y + xv.z*xv.z + xv.w*xv.w;
    #pragma unroll
    for (int m = 1; m <= 32; m <<= 1) { s += __shfl_xor(s, m); ss += __shfl_xor(ss, m); }
    float mu  = s * (1.0f/DIN);
    float inv = rsqrtf(ss * (1.0f/DIN) - mu*mu + 1e-5f);
    float4 wv4 = ((const float4*)lnw)[lane];
    float4 bv4 = ((const float4*)lnb)[lane];
    float4 r4;
    r4.x = (xv.x - mu)*inv*wv4.x + bv4.x;
    r4.y = (xv.y - mu)*inv*wv4.y + bv4.y;
    r4.z = (xv.z - mu)*inv*wv4.z + bv4.z;
    r4.w = (xv.w - mu)*inv*wv4.w + bv4.w;
    *((float4*)&xn[rr][lane*4]) = r4;
    __syncthreads();

    const int col = tid;
    float aq[4] = {0,0,0,0}, ak[4] = {0,0,0,0}, av[4] = {0,0,0,0}, ag[4] = {0,0,0,0};
    for (int i4 = 0; i4 < DIN/4; i4++) {
        float4 x0 = *((const float4*)&xn[0][i4*4]);
        float4 x1 = *((const float4*)&xn[1][i4*4]);
        float4 x2 = *((const float4*)&xn[2][i4*4]);
        float4 x3 = *((const float4*)&xn[3][i4*4]);
        const float* p0 = (const float*)&x0;
        const float* p1 = (const float*)&x1;
        const float* p2 = (const float*)&x2;
        const float* p3 = (const float*)&x3;
        #pragma unroll
        for (int e = 0; e < 4; e++) {
            const int i = i4*4 + e;
            float wq = Wq[i*DIN + col], wk = Wk[i*DIN + col];
            float wvv = Wv[i*DIN + col], wg = Wg[i*DIN + col];
            aq[0] = fmaf(p0[e], wq, aq[0]); aq[1] = fmaf(p1[e], wq, aq[1]);
            aq[2] = fmaf(p2[e], wq, aq[2]); aq[3] = fmaf(p3[e], wq, aq[3]);
            ak[0] = fmaf(p0[e], wk, ak[0]); ak[1] = fmaf(p1[e], wk, ak[1]);
            ak[2] = fmaf(p2[e], wk, ak[2]); ak[3] = fmaf(p3[e], wk, ak[3]);
            av[0] = fmaf(p0[e], wvv, av[0]); av[1] = fmaf(p1[e], wvv, av[1]);
            av[2] = fmaf(p2[e], wvv, av[2]); av[3] = fmaf(p3[e], wvv, av[3]);
            ag[0] = fmaf(p0[e], wg, ag[0]); ag[1] = fmaf(p1[e], wg, ag[1]);
            ag[2] = fmaf(p2[e], wg, ag[2]); ag[3] = fmaf(p3[e], wg, ag[3]);
        }
    }
    const float kscale = 0.17677669529663687f;  // 1/sqrt(DH)
    float bgv = bg[col];
    #pragma unroll
    for (int r = 0; r < 4; r++) {
        const int orow = blockIdx.x*4 + r;
        qb[orow*DIN + col] = aq[r];
        kb[orow*DIN + col] = ak[r] * kscale;
        vb[orow*DIN + col] = av[r];
        gb[orow*DIN + col] = 1.0f/(1.0f + __expf(-(ag[r] + bgv)));
    }
}

// ---------------------------------------------------------------------------
// K2: qk pre-GEMM. qkT[(q*LQ+k)*8+h] = sum_{d in head h} qb[q][d]*kb[k][d].
// Grid (24,24); 32x32 tile; 2x2 micro-tile/thread; per-head static acc.
// Reads q/k tiles ONCE (37 MB total L2 vs 302 MB of per-block re-reads).
// ---------------------------------------------------------------------------
__global__ __launch_bounds__(256) void qk_kernel(
    const float* __restrict__ qb, const float* __restrict__ kb, float* __restrict__ qkT)
{
    __shared__ float q_l[32*260];   // pad 260 -> staggered banks
    __shared__ float k_l[32*260];
    const int tid = threadIdx.x;
    const int bq = blockIdx.x, bk = blockIdx.y;

    {
        const int row = tid >> 3, cg = tid & 7;
        const float4* qs = (const float4*)(qb + (size_t)(bq*32 + row)*DIN + cg*32);
        const float4* ks = (const float4*)(kb + (size_t)(bk*32 + row)*DIN + cg*32);
        #pragma unroll
        for (int j = 0; j < 8; j++) {
            *(float4*)&q_l[row*260 + cg*32 + j*4] = qs[j];
            *(float4*)&k_l[row*260 + cg*32 + j*4] = ks[j];
        }
    }
    __syncthreads();

    const int tx = tid & 15, ty = tid >> 4;
    float acc[2][2][NH];
    #pragma unroll
    for (int a = 0; a < 2; a++)
        #pragma unroll
        for (int b = 0; b < 2; b++)
            #pragma unroll
            for (int h = 0; h < NH; h++) acc[a][b][h] = 0.f;

    #pragma unroll
    for (int d4 = 0; d4 < 64; d4++) {
        const int h = d4 >> 3;   // compile-time per unrolled iter
        float4 q0 = *(const float4*)&q_l[(ty*2+0)*260 + d4*4];
        float4 q1 = *(const float4*)&q_l[(ty*2+1)*260 + d4*4];
        float4 k0 = *(const float4*)&k_l[(tx*2+0)*260 + d4*4];
        float4 k1 = *(const float4*)&k_l[(tx*2+1)*260 + d4*4];
        acc[0][0][h] = fmaf(q0.x,k0.x,acc[0][0][h]); acc[0][0][h] = fmaf(q0.y,k0.y,acc[0][0][h]);
        acc[0][0][h] = fmaf(q0.z,k0.z,acc[0][0][h]); acc[0][0][h] = fmaf(q0.w,k0.w,acc[0][0][h]);
        acc[0][1][h] = fmaf(q0.x,k1.x,acc[0][1][h]); acc[0][1][h] = fmaf(q0.y,k1.y,acc[0][1][h]);
        acc[0][1][h] = fmaf(q0.z,k1.z,acc[0][1][h]); acc[0][1][h] = fmaf(q0.w,k1.w,acc[0][1][h]);
        acc[1][0][h] = fmaf(q1.x,k0.x,acc[1][0][h]); acc[1][0][h] = fmaf(q1.y,k0.y,acc[1][0][h]);
        acc[1][0][h] = fmaf(q1.z,k0.z,acc[1][0][h]); acc[1][0][h] = fmaf(q1.w,k0.w,acc[1][0][h]);
        acc[1][1][h] = fmaf(q1.x,k1.x,acc[1][1][h]); acc[1][1][h] = fmaf(q1.y,k1.y,acc[1][1][h]);
        acc[1][1][h] = fmaf(q1.z,k1.z,acc[1][1][h]); acc[1][1][h] = fmaf(q1.w,k1.w,acc[1][1][h]);
    }

    #pragma unroll
    for (int a = 0; a < 2; a++)
        #pragma unroll
        for (int b = 0; b < 2; b++) {
            size_t base = ((size_t)(bq*32 + ty*2 + a)*LQ + (bk*32 + tx*2 + b))*NH;
            *(float4*)(qkT + base)     = make_float4(acc[a][b][0], acc[a][b][1], acc[a][b][2], acc[a][b][3]);
            *(float4*)(qkT + base + 4) = make_float4(acc[a][b][4], acc[a][b][5], acc[a][b][6], acc[a][b][7]);
        }
}

// ---------------------------------------------------------------------------
// K3: fused bias stream + attention. One block per q-row (768 x 256).
// Thread (key8=tid>>3, dseg=tid&7) owns 16 dims of one key: global float4
// loads deliver slices directly to consuming lanes (no staging LDS at all).
// W2 slice lives in 128 VGPRs; reg double-buffer (T14); 8-lane shfl reduce;
// barrier-free main loop (pT writes lane-disjoint). Tail: softmax/PV/gate/Wo.
// ---------------------------------------------------------------------------
__global__ __launch_bounds__(256, 2) void fused_kernel(
    const float* __restrict__ bias, const float* __restrict__ W2g,
    const float* __restrict__ SCg, const float* __restrict__ qkT,
    const float* __restrict__ vbuf, const float* __restrict__ gbuf,
    const float* __restrict__ Wo, const float* __restrict__ bo,
    float* __restrict__ out)
{
    __shared__ float pT[NH][776];
    __shared__ float ao[DIN];
    __shared__ float isum[NH];

    const int tid  = threadIdx.x;
    const int q    = blockIdx.x;
    const int key8 = tid >> 3;
    const int dseg = tid & 7;

    // preload W2 slice (dims dseg*16..+15, all 8 heads) into regs
    float w2r[16][NH];
    {
        const float4* wp = (const float4*)(W2g + dseg*16*NH);
        #pragma unroll
        for (int j = 0; j < 16; j++) {
            float4 a = wp[j*2], b = wp[j*2+1];
            w2r[j][0]=a.x; w2r[j][1]=a.y; w2r[j][2]=a.z; w2r[j][3]=a.w;
            w2r[j][4]=b.x; w2r[j][5]=b.y; w2r[j][6]=b.z; w2r[j][7]=b.w;
        }
    }
    float Sh[NH], Ch[NH];
    #pragma unroll
    for (int h = 0; h < NH; h++) { Sh[h] = SCg[h]; Ch[h] = SCg[NH+h]; }

    const float* bsrc = bias + (size_t)q*LQ*DB + key8*DB + dseg*16;
    const float* qksrc = qkT + (size_t)q*LQ*NH + key8*NH + dseg;

    float4 va[4], vb4[4];

    #define LOADT(dst, t) {                                         \
        const float4* p = (const float4*)(bsrc + (size_t)(t)*4096); \
        dst[0]=p[0]; dst[1]=p[1]; dst[2]=p[2]; dst[3]=p[3]; }

    #define PROCESS(v, ht) {                                                    \
        float qk = qksrc[(ht)*32*NH];                                           \
        float s = 0.f, ss = 0.f;                                                \
        float acc[NH] = {0,0,0,0,0,0,0,0};                                      \
        _Pragma("unroll")                                                       \
        for (int j = 0; j < 4; j++) {                                           \
            _Pragma("unroll")                                                   \
            for (int e = 0; e < 4; e++) {                                       \
                float xv = (&v[j].x)[e];                                        \
                s += xv; ss = fmaf(xv, xv, ss);                                 \
                _Pragma("unroll")                                               \
                for (int h = 0; h < NH; h++)                                    \
                    acc[h] = fmaf(xv, w2r[j*4+e][h], acc[h]);                   \
            }                                                                   \
        }                                                                       \
        _Pragma("unroll")                                                       \
        for (int m = 1; m <= 4; m <<= 1) {                                      \
            s += __shfl_xor(s, m); ss += __shfl_xor(ss, m);                     \
            _Pragma("unroll")                                                   \
            for (int h = 0; h < NH; h++) acc[h] += __shfl_xor(acc[h], m);       \
        }                                                                       \
        float ah = acc[0], shh = Sh[0], chh = Ch[0];                            \
        _Pragma("unroll")                                                       \
        for (int h = 1; h < NH; h++) {                                          \
            bool psel = (dseg == h);                                            \
            ah = psel ? acc[h] : ah; shh = psel ? Sh[h] : shh;                  \
            chh = psel ? Ch[h] : chh;                                           \
        }                                                                       \
        float mu2  = s * (1.0f/DB);                                             \
        float inv2 = rsqrtf(ss * (1.0f/DB) - mu2*mu2 + 1e-5f);                  \
        float lo = fmaf(inv2, fmaf(-mu2, shh, ah), chh) + qk;                   \
        pT[dseg][(ht)*32 + key8] = lo; }

    LOADT(va, 0);
    for (int hp = 0; hp < 12; hp++) {
        LOADT(vb4, 2*hp + 1);
        PROCESS(va, 2*hp);
        if (hp < 11) LOADT(va, 2*hp + 2);
        PROCESS(vb4, 2*hp + 1);
    }
    #undef LOADT
    #undef PROCESS
    __syncthreads();

    // ---- softmax over keys, per head (8 heads x 32 lanes) ----
    {
        const int h = tid >> 5, l = tid & 31;
        float m = -1e30f;
        for (int i = l; i < LQ; i += 32) m = fmaxf(m, pT[h][i]);
        #pragma unroll
        for (int mm = 1; mm <= 16; mm <<= 1) m = fmaxf(m, __shfl_xor(m, mm));
        float sum = 0.f;
        for (int i = l; i < LQ; i += 32) {
            float e = __expf(pT[h][i] - m);
            pT[h][i] = e;
            sum += e;
        }
        #pragma unroll
        for (int mm = 1; mm <= 16; mm <<= 1) sum += __shfl_xor(sum, mm);
        if (l == 0) isum[h] = 1.0f / sum;
    }
    __syncthreads();

    // ---- PV + gate ----
    {
        const int h = tid >> 5, d = tid & 31;
        const float* vp = vbuf + h*DH + d;
        float a = 0.f;
        for (int k4 = 0; k4 < LQ/4; k4++) {
            float4 p = *(const float4*)&pT[h][k4*4];     // broadcast
            a = fmaf(p.x, vp[(size_t)(k4*4+0)*DIN], a);
            a = fmaf(p.y, vp[(size_t)(k4*4+1)*DIN], a);
            a = fmaf(p.z, vp[(size_t)(k4*4+2)*DIN], a);
            a = fmaf(p.w, vp[(size_t)(k4*4+3)*DIN], a);
        }
        ao[tid] = a * isum[h] * gbuf[(size_t)q*DIN + tid];
    }
    __syncthreads();

    // ---- output projection ----
    {
        float o = bo[tid];
        for (int i = 0; i < DIN; i++) o = fmaf(ao[i], Wo[i*DIN + tid], o);
        out[(size_t)q*DIN + tid] = o;
    }
}

extern "C" void kernel_launch(void* const* d_in, const int* in_sizes, int n_in,
                              void* d_out, int out_size, void* d_ws, size_t ws_size,
                              hipStream_t stream) {
    const float* x    = (const float*)d_in[0];
    const float* bias = (const float*)d_in[1];
    const float* lnw  = (const float*)d_in[2];
    const float* lnb  = (const float*)d_in[3];
    const float* lbw  = (const float*)d_in[4];
    const float* lbb  = (const float*)d_in[5];
    const float* Wq   = (const float*)d_in[6];
    const float* Wk   = (const float*)d_in[7];
    const float* Wv   = (const float*)d_in[8];
    const float* Wb   = (const float*)d_in[9];
    const float* Wg   = (const float*)d_in[10];
    const float* bg   = (const float*)d_in[11];
    const float* Wo   = (const float*)d_in[12];
    const float* bo   = (const float*)d_in[13];

    float* ws = (float*)d_ws;
    float* qb = ws + OFF_QB;
    float* kb = ws + OFF_KB;
    float* vb = ws + OFF_VB;
    float* gb = ws + OFF_GB;
    float* W2 = ws + OFF_W2;
    float* SC = ws + OFF_SC;
    float* qk = ws + OFF_QK;

    projsetup_kernel<<<193, 256, 0, stream>>>(x, lnw, lnb, Wq, Wk, Wv, Wg, bg,
                                              lbw, lbb, Wb, qb, kb, vb, gb, W2, SC);
    qk_kernel<<<dim3(24, 24), 256, 0, stream>>>(qb, kb, qk);
    fused_kernel<<<LQ, 256, 0, stream>>>(bias, W2, SC, qk, vb, gb, Wo, bo, (float*)d_out);
}